// Round 2
// baseline (99.581 us; speedup 1.0000x reference)
//
#include <hip/hip_runtime.h>

#define HW    (768*768)
#define N4    (HW/4)        // 147456 float4 groups per plane per image
#define MAXI  33
#define NBINS (4*MAXI)      // [0..32]=count, [33..65]=sin, [66..98]=cos, [99..131]=r
#define B_IMG 8
#define NTHR  256

// ---------------- Single main pass: per-id binned partial sums ----------------
// loss = sum_id f(id) * S_id, where S_id = sum_{pixels of id, valid} ci * |err|
// and f(id) = 1/max(count,1) * (id>0 ? 1/n_inst : 1). Counts binned here too.
__global__ __launch_bounds__(NTHR) void main_pass(
    const float* __restrict__ pred, const int* __restrict__ inst,
    const float* __restrict__ gtR,  const float* __restrict__ gts,
    const float* __restrict__ gtc,  const float* __restrict__ gci,
    const int* __restrict__ ign,
    float* __restrict__ partials, int nj)
{
    const int b  = blockIdx.y;
    const int gx = gridDim.x;
    __shared__ float bins[NBINS];
    for (int t = threadIdx.x; t < NBINS; t += NTHR) bins[t] = 0.f;
    __syncthreads();

    const size_t off = (size_t)b * HW;
    const int4*   ip  = (const int4*)(inst + off);
    const int4*   gp  = (const int4*)(ign  + off);
    const float4* Rp  = (const float4*)(gtR + off);
    const float4* sp  = (const float4*)(gts + off);
    const float4* cp  = (const float4*)(gtc + off);
    const float4* cip = (const float4*)(gci + off);
    const float4* p0  = (const float4*)(pred + ((size_t)b*3+0)*HW);
    const float4* p1  = (const float4*)(pred + ((size_t)b*3+1)*HW);
    const float4* p2  = (const float4*)(pred + ((size_t)b*3+2)*HW);

    const int step = gx * NTHR;
    const int i0   = blockIdx.x * NTHR + threadIdx.x;

    auto PIX = [&](int id, int gg, float ci, float gs, float gc, float R,
                   float ps, float pc, float pr) {
        if (gg == 0) {
            atomicAdd(&bins[id], 1.0f);           // exact: integer-valued float adds
            if (ci != 0.f) {
                atomicAdd(&bins[33+id], ci * fabsf(ps - gs));
                atomicAdd(&bins[66+id], ci * fabsf(pc - gc));
                atomicAdd(&bins[99+id], ci * fabsf(pr - __logf(R + 1.f)));
            }
        }
    };

    for (int j = 0; j < nj; j += 2) {
        const int ia = i0 + j * step;
        const int ib = ia + step;
        // issue all 18 loads for both groups before any compute
        int4   idA = ip[ia],  idB = ip[ib];
        int4   gA  = gp[ia],  gB  = gp[ib];
        float4 ciA = cip[ia], ciB = cip[ib];
        float4 sA  = sp[ia],  sB  = sp[ib];
        float4 cA  = cp[ia],  cB  = cp[ib];
        float4 RA  = Rp[ia],  RB  = Rp[ib];
        float4 aA  = p0[ia],  aB  = p0[ib];
        float4 bA  = p1[ia],  bB  = p1[ib];
        float4 rA  = p2[ia],  rB  = p2[ib];

        PIX(idA.x, gA.x, ciA.x, sA.x, cA.x, RA.x, aA.x, bA.x, rA.x);
        PIX(idA.y, gA.y, ciA.y, sA.y, cA.y, RA.y, aA.y, bA.y, rA.y);
        PIX(idA.z, gA.z, ciA.z, sA.z, cA.z, RA.z, aA.z, bA.z, rA.z);
        PIX(idA.w, gA.w, ciA.w, sA.w, cA.w, RA.w, aA.w, bA.w, rA.w);
        PIX(idB.x, gB.x, ciB.x, sB.x, cB.x, RB.x, aB.x, bB.x, rB.x);
        PIX(idB.y, gB.y, ciB.y, sB.y, cB.y, RB.y, aB.y, bB.y, rB.y);
        PIX(idB.z, gB.z, ciB.z, sB.z, cB.z, RB.z, aB.z, bB.z, rB.z);
        PIX(idB.w, gB.w, ciB.w, sB.w, cB.w, RB.w, aB.w, bB.w, rB.w);
    }

    __syncthreads();
    float* pp = partials + ((size_t)(b * gx + blockIdx.x)) * NBINS;
    for (int t = threadIdx.x; t < NBINS; t += NTHR) pp[t] = bins[t];
}

// ---------------- Finalize: deterministic reduce over blocks + weighting ----------------
__global__ __launch_bounds__(NTHR) void finalize(
    const float* __restrict__ partials, float* __restrict__ out, int gx)
{
    const int b = blockIdx.x;
    __shared__ float red[NBINS];
    if (threadIdx.x < NBINS) {
        float acc = 0.f;
        const float* pp = partials + (size_t)b * gx * NBINS + threadIdx.x;
        for (int k = 0; k < gx; ++k) acc += pp[(size_t)k * NBINS];
        red[threadIdx.x] = acc;
    }
    __syncthreads();
    if (threadIdx.x == 0) {
        float n = 0.f;
        for (int id = 1; id < MAXI; ++id) n += (red[id] > 0.f) ? 1.f : 0.f;
        n = fmaxf(n, 1.f);
        float ts = 0.f, tc = 0.f, tr = 0.f;
        for (int id = 0; id < MAXI; ++id) {
            float sz = fmaxf(red[id], 1.f);
            float f  = (id > 0) ? 1.f / (sz * n) : 1.f / sz;
            ts += f * red[33 + id];
            tc += f * red[66 + id];
            tr += f * red[99 + id];
        }
        float tot = ts + tc + tr;
        out[     b] = tot;
        out[ 8 + b] = 0.f;
        out[16 + b] = tot;
        out[24 + b] = 0.f;
        out[32 + b] = ts;
        out[40 + b] = tc;
        out[48 + b] = tr;
        out[56 + b] = 0.f;
    }
}

extern "C" void kernel_launch(void* const* d_in, const int* in_sizes, int n_in,
                              void* d_out, int out_size, void* d_ws, size_t ws_size,
                              hipStream_t stream) {
    const float* pred = (const float*)d_in[0];
    const int*   inst = (const int*)d_in[1];
    // d_in[2] = label (unused by the reference)
    const float* gtR  = (const float*)d_in[3];
    const float* gts  = (const float*)d_in[4];
    const float* gtc  = (const float*)d_in[5];
    const float* gci  = (const float*)d_in[6];
    const int*   ign  = (const int*)d_in[7];
    float* out = (float*)d_out;

    // pick largest gx whose partials fit in workspace (all divide N4 exactly,
    // and give an even per-thread group count for the 2-deep batched loop)
    int gx = 144;                                         // nj = 4
    if ((size_t)B_IMG * gx * NBINS * sizeof(float) > ws_size) gx = 72;   // nj = 8
    if ((size_t)B_IMG * gx * NBINS * sizeof(float) > ws_size) gx = 36;   // nj = 16
    const int nj = N4 / (gx * NTHR);

    dim3 grid(gx, B_IMG);
    main_pass<<<grid, NTHR, 0, stream>>>(pred, inst, gtR, gts, gtc, gci, ign,
                                         (float*)d_ws, nj);
    finalize<<<B_IMG, NTHR, 0, stream>>>((const float*)d_ws, out, gx);
}